// Round 4
// baseline (262.099 us; speedup 1.0000x reference)
//
#include <hip/hip_runtime.h>
#include <math.h>

// Problem constants (from reference setup_inputs).
constexpr int B_ = 2048;
constexpr int C_ = 9605;
constexpr int L_ = 8;
constexpr int TOPK_ = 16;
constexpr int CAP_ = 512;       // LDS candidate capacity (expected ~219 per row, 20 sigma margin)
constexpr float T0_ = 2.0f;     // candidate prefilter threshold (16th largest ~2.95)
constexpr int QW_ = 2404;       // packed-code quads per rotation (>= max n4 + 1)
constexpr int NQ_ = (B_ * C_) / 4;  // 4,917,760 flat quads (exactly divisible)

__device__ __forceinline__ float sigm(float v) { return 1.0f / (1.0f + expf(-v)); }

// our_rank_loss: d = x2 - x1 + margin; s = sigmoid(5d); 2s when violated (d>0)
__device__ __forceinline__ float rank_loss(float x1, float x2) {
  float d = x2 - x1 + 0.05f;
  float s = 1.0f / (1.0f + expf(-5.0f * d));
  return (d > 0.0f) ? 2.0f * s : s;
}

// Order-preserving float->uint key (ascending) and inverse.
__device__ __forceinline__ unsigned int fkey(float v) {
  unsigned int u = __float_as_uint(v);
  return u ^ ((u & 0x80000000u) ? 0xFFFFFFFFu : 0x80000000u);
}
__device__ __forceinline__ float fkeyinv(unsigned int k) {
  unsigned int u = (k & 0x80000000u) ? (k ^ 0x80000000u) : ~k;
  return __uint_as_float(u);
}

// Kernel 0a: group_mask [L, C] int32 (bool promoted) -> per-class code byte.
__global__ void build_code_kernel(const int* __restrict__ mask,
                                  unsigned char* __restrict__ code) {
  int c = blockIdx.x * 256 + threadIdx.x;
  if (c >= C_) return;
  unsigned char cd = 0xFF;
#pragma unroll
  for (int l = L_ - 1; l >= 0; --l)
    if (mask[l * C_ + c] != 0) cd = (unsigned char)l;
  code[c] = cd;
}

// Kernel 0b: rotated packed code tables. codeq[r][k] packs codes of classes
// (r+4k .. r+4k+3) so a row whose interior starts at class `lead` reads one
// aligned dword per quad.
__global__ void pack_code_kernel(const unsigned char* __restrict__ code,
                                 unsigned int* __restrict__ codeq) {
  int k = blockIdx.x * 256 + threadIdx.x;
  int r = blockIdx.y;
  if (k >= QW_) return;
  unsigned int v = 0u;
#pragma unroll
  for (int e = 0; e < 4; ++e) {
    int c = r + 4 * k + e;
    unsigned int byte = (c < C_) ? (unsigned int)code[c] : 0xFFu;
    v |= byte << (8 * e);
  }
  codeq[r * QW_ + k] = v;
}

// Kernel A: flat stream over y (blockIdx.y==0) / y_neg (==1). Pure-BW scan:
// 4 independent float4 loads in flight; rare path (positives ~0.15%) computes
// row/group and atomicOrs the per-row gt bit-mask in global ws.
__global__ void __launch_bounds__(256) scan_pos_kernel(
    const float* __restrict__ y, const float* __restrict__ yn,
    const unsigned char* __restrict__ code,
    unsigned int* __restrict__ gtb, unsigned int* __restrict__ gnb) {
  const float* arr = (blockIdx.y == 0) ? y : yn;
  unsigned int* dst = (blockIdx.y == 0) ? gtb : gnb;
  const float4* a4 = reinterpret_cast<const float4*>(arr);
  const int S = gridDim.x * 256;
  int q = blockIdx.x * 256 + threadIdx.x;

  auto rare = [&](float v, int idx) {
    if (v > 0.0f) {
      int row = idx / C_;                 // constexpr divisor -> magic mul
      int col = idx - row * C_;
      unsigned char cd = code[col];
      if (cd < L_) atomicOr(&dst[row], 1u << cd);
    }
  };
  auto chk = [&](float4 v, int qq) {
    float m = fmaxf(fmaxf(v.x, v.y), fmaxf(v.z, v.w));
    if (m > 0.0f) {
      int base = qq << 2;
      rare(v.x, base); rare(v.y, base + 1); rare(v.z, base + 2); rare(v.w, base + 3);
    }
  };

  for (; q + 3 * S < NQ_; q += 4 * S) {
    float4 v0 = a4[q];
    float4 v1 = a4[q + S];
    float4 v2 = a4[q + 2 * S];
    float4 v3 = a4[q + 3 * S];
    chk(v0, q); chk(v1, q + S); chk(v2, q + 2 * S); chk(v3, q + 3 * S);
  }
  for (; q < NQ_; q += S) chk(a4[q], q);
}

// Kernel B: one block per row; x + packed codes only. Unroll-4 load batches
// (80 B in flight/lane), register 8-slot group max, rare-branch LDS candidate
// append; wave shuffle reduction; exact 16th-largest; loss epilogue.
__global__ void __launch_bounds__(256) row_loss_kernel(
    const float* __restrict__ x, const unsigned char* __restrict__ code,
    const unsigned int* __restrict__ codeq,
    const unsigned int* __restrict__ gtb_g, const unsigned int* __restrict__ gnb_g,
    float* __restrict__ loss) {
  __shared__ float cand[CAP_];
  __shared__ int cand_cnt;
  __shared__ float wgm[4][L_];
  __shared__ float s_x16;
  __shared__ int s_red;

  const int t = threadIdx.x;
  const int b = blockIdx.x;
  const float* xr = x + (size_t)b * C_;
  if (t == 0) cand_cnt = 0;

  float gm[L_];
#pragma unroll
  for (int l = 0; l < L_; ++l) gm[l] = -INFINITY;

  auto cappend = [&](float xv) {         // call only under (xv > T0_)
    int p = atomicAdd(&cand_cnt, 1);
    if (p < CAP_) cand[p] = xv;
  };
  auto procq = [&](float4 xv, unsigned int cd4) {
    int c0 = (int)(cd4 & 0xFF), c1 = (int)((cd4 >> 8) & 0xFF);
    int c2 = (int)((cd4 >> 16) & 0xFF), c3 = (int)((cd4 >> 24) & 0xFF);
#pragma unroll
    for (int l = 0; l < L_; ++l) {
      float vl = (c0 == l) ? xv.x : -INFINITY;
      vl = (c1 == l) ? fmaxf(vl, xv.y) : vl;
      vl = (c2 == l) ? fmaxf(vl, xv.z) : vl;
      vl = (c3 == l) ? fmaxf(vl, xv.w) : vl;
      gm[l] = fmaxf(gm[l], vl);
    }
    if (xv.x > T0_) cappend(xv.x);
    if (xv.y > T0_) cappend(xv.y);
    if (xv.z > T0_) cappend(xv.z);
    if (xv.w > T0_) cappend(xv.w);
  };

  // Interior: aligned float4 body. Row offset in first quad: (b*C)%4 = b%4.
  const int lead = (4 - (b & 3)) & 3;
  const int n4 = (C_ - lead) >> 2;
  const float4* x4 = reinterpret_cast<const float4*>(x) + (((size_t)b * C_ + lead) >> 2);
  const unsigned int* cq = codeq + lead * QW_;

  // Unroll-4 batches cover k < 2048 (n4 is 2400/2401, so both batches full).
  for (int kb = 0; kb < 2048; kb += 1024) {
    int k0 = kb + t, k1 = kb + 256 + t, k2 = kb + 512 + t, k3 = kb + 768 + t;
    float4 a0 = x4[k0];
    float4 a1 = x4[k1];
    float4 a2 = x4[k2];
    float4 a3 = x4[k3];
    unsigned int q0 = cq[k0], q1 = cq[k1], q2 = cq[k2], q3 = cq[k3];
    procq(a0, q0); procq(a1, q1); procq(a2, q2); procq(a3, q3);
  }
  // Tail quads [2048, n4).
  for (int k = 2048 + t; k < n4; k += 256) procq(x4[k], cq[k]);

  // Head (classes [0,lead)) and tail scalars (classes [lead+4*n4, C)).
  if (t < lead) {
    float v = xr[t];
    int cd = (int)code[t];
#pragma unroll
    for (int l = 0; l < L_; ++l)
      if (cd == l) gm[l] = fmaxf(gm[l], v);
    if (v > T0_) cappend(v);
  }
  const int tstart = lead + (n4 << 2);
  if (t >= 4 && t < 4 + (C_ - tstart)) {
    int c = tstart + (t - 4);
    float v = xr[c];
    int cd = (int)code[c];
#pragma unroll
    for (int l = 0; l < L_; ++l)
      if (cd == l) gm[l] = fmaxf(gm[l], v);
    if (v > T0_) cappend(v);
  }

  // Wave-level max reduction (width 64).
#pragma unroll
  for (int off = 32; off > 0; off >>= 1) {
#pragma unroll
    for (int l = 0; l < L_; ++l) gm[l] = fmaxf(gm[l], __shfl_xor(gm[l], off, 64));
  }
  if ((t & 63) == 0) {
    int w = t >> 6;
#pragma unroll
    for (int l = 0; l < L_; ++l) wgm[w][l] = gm[l];
  }
  __syncthreads();

  const int cnt = cand_cnt;
  const bool mainp = (cnt >= TOPK_) && (cnt <= CAP_);
  if (mainp) {
    if (t < 64) {  // wave 0: binary search on ordered keys, candidates in regs
      unsigned int ku[CAP_ / 64];
#pragma unroll
      for (int k = 0; k < CAP_ / 64; ++k) {
        int idx = t + (k << 6);
        ku[k] = (idx < cnt) ? fkey(cand[idx]) : 0u;
      }
      unsigned int lo = 0u, hi = 0xFFFFFFFFu;
      for (int it = 0; it < 32 && lo < hi; ++it) {
        unsigned int mid = lo + ((hi - lo) >> 1) + 1u;
        int c16 = 0;
#pragma unroll
        for (int k = 0; k < CAP_ / 64; ++k) c16 += (ku[k] >= mid) ? 1 : 0;
#pragma unroll
        for (int off = 32; off > 0; off >>= 1) c16 += __shfl_xor(c16, off, 64);
        if (c16 >= TOPK_) lo = mid; else hi = mid - 1u;
      }
      if (t == 0) s_x16 = fkeyinv(lo);
    }
  } else {
    // Fallback (statistically never): exact block-wide counting binary search
    // re-reading the row. Block-uniform control flow -> barriers safe.
    unsigned int lo = 0u, hi = 0xFFFFFFFFu;
    for (int it = 0; it < 32; ++it) {
      if (lo >= hi) break;
      unsigned int mid = lo + ((hi - lo) >> 1) + 1u;
      if (t == 0) s_red = 0;
      __syncthreads();
      int cl = 0;
      for (int c = t; c < C_; c += 256) cl += (fkey(xr[c]) >= mid) ? 1 : 0;
      atomicAdd(&s_red, cl);
      __syncthreads();
      int total = s_red;
      __syncthreads();
      if (total >= TOPK_) lo = mid; else hi = mid - 1u;
    }
    if (t == 0) s_x16 = fkeyinv(lo);
  }
  __syncthreads();

  // Epilogue: combine 4 wave partials + gt bits from kernel A, 10 rank-losses.
  if (t == 0) {
    float thres = fmaxf(sigm(s_x16), 0.3f);
    unsigned int gtbf = gtb_g[b];
    unsigned int gnbf = gnb_g[b];
    float caseB = 0.0f, unio = -INFINITY, negmax = -INFINITY;
#pragma unroll
    for (int l = 0; l < L_; ++l) {
      float gx = fmaxf(fmaxf(wgm[0][l], wgm[1][l]), fmaxf(wgm[2][l], wgm[3][l]));
      float g = sigm(gx);
      unio = fmaxf(unio, g);
      caseB += ((gtbf >> l) & 1u) ? rank_loss(g, thres) : rank_loss(thres, g);
      if ((gnbf >> l) & 1u) negmax = fmaxf(negmax, g);
    }
    float negscore = (gnbf != 0u) ? negmax : 0.0f;
    float caseA = 0.5f * rank_loss(thres, unio) + 0.5f * rank_loss(thres, negscore);
    loss[b] = (gtbf != 0u) ? caseB : caseA;
  }
}

// Kernel 2: deterministic mean of the 2048 per-row losses.
__global__ void mean_kernel(const float* __restrict__ loss, float* __restrict__ out) {
  const int t = threadIdx.x;
  float s = 0.0f;
  for (int i = t; i < B_; i += 256) s += loss[i];
#pragma unroll
  for (int off = 32; off > 0; off >>= 1) s += __shfl_xor(s, off, 64);
  __shared__ float part[4];
  if ((t & 63) == 0) part[t >> 6] = s;
  __syncthreads();
  if (t == 0) out[0] = (part[0] + part[1] + part[2] + part[3]) * (1.0f / (float)B_);
}

extern "C" void kernel_launch(void* const* d_in, const int* in_sizes, int n_in,
                              void* d_out, int out_size, void* d_ws, size_t ws_size,
                              hipStream_t stream) {
  const float* x = (const float*)d_in[0];
  const float* y = (const float*)d_in[1];
  const float* yn = (const float*)d_in[2];
  const int* mask = (const int*)d_in[3];  // bool promoted to int32 by harness

  char* ws = (char*)d_ws;
  float* loss = (float*)ws;                         // [0, 8192)
  unsigned int* gtb = (unsigned int*)(ws + 8192);   // [8192, 16384)
  unsigned int* gnb = (unsigned int*)(ws + 16384);  // [16384, 24576)
  unsigned char* code = (unsigned char*)(ws + 24576);          // 9605 B -> pad 9632
  unsigned int* codeq = (unsigned int*)(ws + 24576 + 9632);    // 4*QW_*4 B

  hipMemsetAsync(gtb, 0, 2 * B_ * sizeof(unsigned int), stream);  // gtb+gnb contiguous
  hipLaunchKernelGGL(build_code_kernel, dim3((C_ + 255) / 256), dim3(256), 0, stream,
                     mask, code);
  hipLaunchKernelGGL(pack_code_kernel, dim3((QW_ + 255) / 256, 4), dim3(256), 0, stream,
                     code, codeq);
  hipLaunchKernelGGL(scan_pos_kernel, dim3(2048, 2), dim3(256), 0, stream,
                     y, yn, code, gtb, gnb);
  hipLaunchKernelGGL(row_loss_kernel, dim3(B_), dim3(256), 0, stream,
                     x, code, codeq, gtb, gnb, loss);
  hipLaunchKernelGGL(mean_kernel, dim3(1), dim3(256), 0, stream,
                     loss, (float*)d_out);
}